// Round 5
// baseline (371.664 us; speedup 1.0000x reference)
//
#include <hip/hip_runtime.h>
#include <stdint.h>
#include <math.h>

// Native vector types — __builtin_nontemporal_{load,store} requires a native
// vector, not HIP's float4 class.
typedef float vf4 __attribute__((ext_vector_type(4)));
typedef float vf2 __attribute__((ext_vector_type(2)));

__device__ __forceinline__ void mm4(vf4 v, float& mn, float& mx) {
    mn = fminf(mn, fminf(fminf(v.x, v.y), fminf(v.z, v.w)));
    mx = fmaxf(mx, fmaxf(fmaxf(v.x, v.y), fmaxf(v.z, v.w)));
}

__device__ __forceinline__ vf4 q4(vf4 v, float mn, float scale, float inv_scale) {
    vf4 r;
    r.x = rintf((v.x - mn) * scale) * inv_scale + mn;
    r.y = rintf((v.y - mn) * scale) * inv_scale + mn;
    r.z = rintf((v.z - mn) * scale) * inv_scale + mn;
    r.w = rintf((v.w - mn) * scale) * inv_scale + mn;
    return r;
}

// One tile = 2048 vf4 = 32 KB, covered by 256 threads x 8 vf4.
// Thread t's 8 loads are at tile + t + {0..7}*256: each load instruction is
// fully wave-coalesced (64 lanes x 16 B contiguous = 8 cache lines), and the
// 8 instructions touch disjoint lines.
#define TILE_V4 2048u

// ---------------------------------------------------------------------------
// Pass 1: per-block min/max partial.
// Round-4 diagnosis: all previous passes ran at ~1.7 TB/s because the inner
// loop kept only 4 loads in flight per wave (issue-4 / drain-4 / branch —
// zero cross-iteration MLP). The harness's own fillBuffer hits 6.5 TB/s at
// 9.7% occupancy because stores never wait. This version mimics that shape:
// 8 back-to-back independent loads per tile (8 KB/wave in flight), exactly
// one tile per block for this shape (grid 6272 = n4/2048), so there is no
// inner loop at all — the block scheduler provides cross-tile pipelining.
// ---------------------------------------------------------------------------
__global__ __launch_bounds__(256) void minmax_partial8(
    const float* __restrict__ x, long n,
    vf2* __restrict__ ws)
{
    const vf4* __restrict__ x4 = (const vf4*)x;
    const unsigned n4 = (unsigned)(n >> 2);
    const unsigned tid = threadIdx.x;

    float mn0 = INFINITY, mn1 = INFINITY, mn2 = INFINITY, mn3 = INFINITY;
    float mn4_ = INFINITY, mn5 = INFINITY, mn6 = INFINITY, mn7 = INFINITY;
    float mx0 = -INFINITY, mx1 = -INFINITY, mx2 = -INFINITY, mx3 = -INFINITY;
    float mx4_ = -INFINITY, mx5 = -INFINITY, mx6 = -INFINITY, mx7 = -INFINITY;

    // Grid-stride over tiles (exactly 1 tile/block for this shape).
    for (unsigned t = blockIdx.x; (unsigned long)t * TILE_V4 < n4; t += gridDim.x) {
        const unsigned b0 = t * TILE_V4;
        if (b0 + TILE_V4 <= n4) {
            const unsigned base = b0 + tid;
            // 8 independent loads, issued before any consumption.
            vf4 v0 = x4[base];
            vf4 v1 = x4[base + 256u];
            vf4 v2 = x4[base + 512u];
            vf4 v3 = x4[base + 768u];
            vf4 v4 = x4[base + 1024u];
            vf4 v5 = x4[base + 1280u];
            vf4 v6 = x4[base + 1536u];
            vf4 v7 = x4[base + 1792u];
            mm4(v0, mn0, mx0);
            mm4(v1, mn1, mx1);
            mm4(v2, mn2, mx2);
            mm4(v3, mn3, mx3);
            mm4(v4, mn4_, mx4_);
            mm4(v5, mn5, mx5);
            mm4(v6, mn6, mx6);
            mm4(v7, mn7, mx7);
        } else {
            for (unsigned idx = b0 + tid; idx < n4; idx += 256u)
                mm4(x4[idx], mn0, mx0);
        }
    }
    // Scalar tail (n % 4 != 0) — not hit for this shape, kept for generality.
    for (long i = (long)n4 * 4 + (long)blockIdx.x * 256 + tid; i < n;
         i += (long)gridDim.x * 256)
    {
        float v = x[i];
        mn0 = fminf(mn0, v); mx0 = fmaxf(mx0, v);
    }

    float mn = fminf(fminf(fminf(mn0, mn1), fminf(mn2, mn3)),
                     fminf(fminf(mn4_, mn5), fminf(mn6, mn7)));
    float mx = fmaxf(fmaxf(fmaxf(mx0, mx1), fmaxf(mx2, mx3)),
                     fmaxf(fmaxf(mx4_, mx5), fmaxf(mx6, mx7)));
    #pragma unroll
    for (int off = 32; off > 0; off >>= 1) {
        mn = fminf(mn, __shfl_down(mn, off, 64));
        mx = fmaxf(mx, __shfl_down(mx, off, 64));
    }
    __shared__ float smn[4], smx[4];
    const int wave = tid >> 6;
    const int lane = tid & 63;
    if (lane == 0) { smn[wave] = mn; smx[wave] = mx; }
    __syncthreads();
    if (tid == 0) {
        vf2 p;
        p.x = fminf(fminf(smn[0], smn[1]), fminf(smn[2], smn[3]));
        p.y = fmaxf(fmaxf(smx[0], smx[1]), fmaxf(smx[2], smx[3]));
        ws[blockIdx.x] = p;   // plain store; kernel-end flush publishes it
    }
}

// ---------------------------------------------------------------------------
// Middle: single-block reduce of nb partials -> res[0]=min, res[1]=max.
// nb <= ~6272: 256 threads x ~25 independent 8-B loads, a few µs.
// (Avoids every quant block redundantly re-reading nb*8 B of partials.)
// ---------------------------------------------------------------------------
__global__ __launch_bounds__(256) void reduce_partials(
    const vf2* __restrict__ ws, unsigned nb,
    float* __restrict__ res)
{
    const unsigned tid = threadIdx.x;
    float mn = INFINITY, mx = -INFINITY;
    for (unsigned i = tid; i < nb; i += 256u) {
        vf2 p = ws[i];
        mn = fminf(mn, p.x);
        mx = fmaxf(mx, p.y);
    }
    #pragma unroll
    for (int off = 32; off > 0; off >>= 1) {
        mn = fminf(mn, __shfl_down(mn, off, 64));
        mx = fmaxf(mx, __shfl_down(mx, off, 64));
    }
    __shared__ float smn[4], smx[4];
    const int wave = tid >> 6;
    const int lane = tid & 63;
    if (lane == 0) { smn[wave] = mn; smx[wave] = mx; }
    __syncthreads();
    if (tid == 0) {
        res[0] = fminf(fminf(smn[0], smn[1]), fminf(smn[2], smn[3]));
        res[1] = fmaxf(fmaxf(smx[0], smx[1]), fmaxf(smx[2], smx[3]));
    }
}

// ---------------------------------------------------------------------------
// Pass 2: quantize. Same tile geometry (8 loads in flight, then 8 NT
// stores — stores never wait). Input re-read hits the 256 MB L3 (verified
// round 1: FETCH_SIZE == 1x input across both passes); NT stores keep
// write-allocate from evicting it.
// ---------------------------------------------------------------------------
__global__ __launch_bounds__(256) void quant8(
    const float* __restrict__ x, long n,
    float* __restrict__ o,
    const float* __restrict__ res)
{
    const vf4* __restrict__ x4 = (const vf4*)x;
    vf4* __restrict__ o4 = (vf4*)o;
    const unsigned n4 = (unsigned)(n >> 2);
    const unsigned tid = threadIdx.x;

    const float fmn = res[0];
    const float fmx = res[1];
    const float scale = 255.0f / (fmx - fmn);
    const float inv_scale = 1.0f / scale;

    for (unsigned t = blockIdx.x; (unsigned long)t * TILE_V4 < n4; t += gridDim.x) {
        const unsigned b0 = t * TILE_V4;
        if (b0 + TILE_V4 <= n4) {
            const unsigned base = b0 + tid;
            vf4 v0 = x4[base];
            vf4 v1 = x4[base + 256u];
            vf4 v2 = x4[base + 512u];
            vf4 v3 = x4[base + 768u];
            vf4 v4 = x4[base + 1024u];
            vf4 v5 = x4[base + 1280u];
            vf4 v6 = x4[base + 1536u];
            vf4 v7 = x4[base + 1792u];
            __builtin_nontemporal_store(q4(v0, fmn, scale, inv_scale), &o4[base]);
            __builtin_nontemporal_store(q4(v1, fmn, scale, inv_scale), &o4[base + 256u]);
            __builtin_nontemporal_store(q4(v2, fmn, scale, inv_scale), &o4[base + 512u]);
            __builtin_nontemporal_store(q4(v3, fmn, scale, inv_scale), &o4[base + 768u]);
            __builtin_nontemporal_store(q4(v4, fmn, scale, inv_scale), &o4[base + 1024u]);
            __builtin_nontemporal_store(q4(v5, fmn, scale, inv_scale), &o4[base + 1280u]);
            __builtin_nontemporal_store(q4(v6, fmn, scale, inv_scale), &o4[base + 1536u]);
            __builtin_nontemporal_store(q4(v7, fmn, scale, inv_scale), &o4[base + 1792u]);
        } else {
            for (unsigned idx = b0 + tid; idx < n4; idx += 256u)
                __builtin_nontemporal_store(q4(x4[idx], fmn, scale, inv_scale), &o4[idx]);
        }
    }
    // Scalar tail (n % 4 != 0) — not hit for this shape.
    for (long i = (long)n4 * 4 + (long)blockIdx.x * 256 + tid; i < n;
         i += (long)gridDim.x * 256)
        o[i] = rintf((x[i] - fmn) * scale) * inv_scale + fmn;
}

extern "C" void kernel_launch(void* const* d_in, const int* in_sizes, int n_in,
                              void* d_out, int out_size, void* d_ws, size_t ws_size,
                              hipStream_t stream) {
    const float* x = (const float*)d_in[0];
    float* out = (float*)d_out;
    const long n = (long)in_sizes[0];
    const unsigned n4 = (unsigned)(n / 4);

    // One block per 2048-vf4 tile: n4 = 12,845,056 = 6272 * 2048 exactly.
    unsigned tiles = (n4 + TILE_V4 - 1u) / TILE_V4;
    if (tiles == 0) tiles = 1;
    unsigned grid = tiles;
    // Workspace: grid partials (8 B) + 2 result floats.
    const size_t need = (size_t)grid * sizeof(vf2) + 2 * sizeof(float);
    if (ws_size < need) {
        size_t cap = (ws_size > 2 * sizeof(float))
                         ? (ws_size - 2 * sizeof(float)) / sizeof(vf2) : 64;
        if (cap < 64) cap = 64;
        if ((size_t)grid > cap) grid = (unsigned)cap;   // blocks then loop tiles
    }

    vf2* ws = (vf2*)d_ws;
    float* res = (float*)((char*)d_ws + (size_t)grid * sizeof(vf2));

    minmax_partial8<<<grid, 256, 0, stream>>>(x, n, ws);
    reduce_partials<<<1, 256, 0, stream>>>(ws, grid, res);
    quant8<<<grid, 256, 0, stream>>>(x, n, out, res);
}